// Round 9
// baseline (34.954 us; speedup 1.0000x reference)
//
#include <hip/hip_runtime.h>

#ifndef __has_builtin
#define __has_builtin(x) 0
#endif

#if __has_builtin(__builtin_amdgcn_sdot4)
#define DOT4(a, b, c) __builtin_amdgcn_sdot4((a), (b), (c), false)
#else
__device__ __forceinline__ int dot4_sw(int a, int b, int c) {
#pragma unroll
    for (int k = 0; k < 4; ++k)
        c += (int)(signed char)((a >> (8 * k)) & 0xff) *
             (int)(signed char)((b >> (8 * k)) & 0xff);
    return c;
}
#define DOT4(a, b, c) dot4_sw((a), (b), (c))
#endif

constexpr int CH   = 256;
constexpr int NPIX = 1024;   // 32*32
constexpr int LW   = 33;     // LDS row stride (ints): <=2-way bank alias (free)
constexpr float BN_EPS = 1e-5f;

__device__ __forceinline__ float rfl_f(float v) {
    return __int_as_float(__builtin_amdgcn_readfirstlane(__float_as_int(v)));
}

// One block per (image-pair, group); 256 threads, 4 px each, 2 images.
// Each thread loads ONLY its own row (4 ch), packs sign-bytes once, and rows
// are exchanged through a packed LDS plane (no 3x global re-read, no 3x pack).
// Halo handled by cndmask on LDS reads. Weights/BN set up once per block.
__global__ __launch_bounds__(256, 4)
void bconv(const float* __restrict__ x,
           const float* __restrict__ wgt,
           const float* __restrict__ gamma,
           const float* __restrict__ beta,
           const float* __restrict__ rmean,
           const float* __restrict__ rvar,
           float* __restrict__ out) {
    __shared__ int   pk_lds[2][32][LW];  // packed int8x4 (over ci) per pixel
    __shared__ int   wq_lds[36];         // packed weights [c2*9+tap]
    __shared__ float bn_lds[8];          // inv[4], bias[4]

    const int tid  = threadIdx.x;
    const int n0   = (blockIdx.x >> 6) * 2;
    const int g    = blockIdx.x & 63;
    const int pix0 = tid * 4;
    const int row  = pix0 >> 5;
    const int col0 = pix0 & 31;
    const float* xnA = x + n0 * CH * NPIX;
    const float* xnB = xnA + CH * NPIX;
    float* onA = out + n0 * CH * NPIX;
    float* onB = onA + CH * NPIX;

    // ---- issue ALL 16 global loads upfront (max MLP) ----
    float4 xvA[4], scA[4], xvB[4], scB[4];
#pragma unroll
    for (int ci = 0; ci < 4; ++ci)
        xvA[ci] = *(const float4*)(xnA + (g * 4 + ci) * NPIX + pix0);
#pragma unroll
    for (int c2 = 0; c2 < 4; ++c2)
        scA[c2] = *(const float4*)(xnA + (c2 * 64 + g) * NPIX + pix0);
#pragma unroll
    for (int ci = 0; ci < 4; ++ci)
        xvB[ci] = *(const float4*)(xnB + (g * 4 + ci) * NPIX + pix0);
#pragma unroll
    for (int c2 = 0; c2 < 4; ++c2)
        scB[c2] = *(const float4*)(xnB + (c2 * 64 + g) * NPIX + pix0);

    // ---- weight pack (144 lanes) + BN consts (4 lanes), once per block ----
    if (tid < 144) {
        const int c2 = tid / 36, r = tid % 36, ci = r / 9, tap = r % 9;
        float w = wgt[g * 144 + tid];   // [co][ci][3][3], co = g*4+c2
        int s = (w > 0.f) ? 1 : ((w < 0.f) ? -1 : 0);
        ((char*)wq_lds)[(c2 * 9 + tap) * 4 + ci] = (char)s;
    } else if (tid < 148) {
        const int ci = tid - 144, c = g * 4 + ci;
        float r  = __fdiv_rn(1.0f, __fsqrt_rn(__fadd_rn(rvar[c], BN_EPS)));
        float iv = __fmul_rn(gamma[c], r);
        bn_lds[ci]     = iv;
        bn_lds[4 + ci] = __fsub_rn(beta[c], __fmul_rn(rmean[c], iv));
    }

    // BN consts needed before pack-A: pull via LDS after implicit availability?
    // They are produced by lanes 144..147 pre-barrier; pack-A happens pre-barrier
    // too, so compute BN consts redundantly per-thread instead (cheap: 4 chans).
    float inv[4], bias[4];
#pragma unroll
    for (int ci = 0; ci < 4; ++ci) {
        const int c = g * 4 + ci;
        float r  = __fdiv_rn(1.0f, __fsqrt_rn(__fadd_rn(rvar[c], BN_EPS)));
        inv[ci]  = __fmul_rn(gamma[c], r);
        bias[ci] = __fsub_rn(beta[c], __fmul_rn(rmean[c], inv[ci]));
    }

    // pack own row of image I into LDS plane I
    auto pack_to_lds = [&](const float4 xv[4], int img) {
#pragma unroll
        for (int p = 0; p < 4; ++p) {
            int v = 0;
#pragma unroll
            for (int ci = 0; ci < 4; ++ci) {
                float h = __fadd_rn(__fmul_rn(((const float*)&xv[ci])[p], inv[ci]), bias[ci]);
                int s = (h > 0.f) ? 1 : ((h < 0.f) ? -1 : 0);
                v |= (s & 0xff) << (8 * ci);
            }
            pk_lds[img][row][col0 + p] = v;
        }
    };

    pack_to_lds(xvA, 0);
    __syncthreads();   // bar1: weights + plane A visible

    // uniform weights -> SGPRs
    int wq[4][9];
#pragma unroll
    for (int c2 = 0; c2 < 4; ++c2)
#pragma unroll
        for (int t = 0; t < 9; ++t)
            wq[c2][t] = __builtin_amdgcn_readfirstlane(wq_lds[c2 * 9 + t]);

    const bool le = (col0 == 0), re = (col0 == 28);

    // gather 3x8 packed window from LDS plane (halo masked, addr clamped)
    auto gather = [&](int img, int a[3][8]) {
#pragma unroll
        for (int kh = 0; kh < 3; ++kh) {
            const int rs  = row + 2 * kh - 2;
            const int rr  = min(max(rs, 0), 31);
            const bool okr = (unsigned)rs < 32u;
#pragma unroll
            for (int j = 0; j < 8; ++j) {
                const int c  = col0 - 2 + j;
                const int cc = min(max(c, 0), 31);
                const bool okc = !(j < 2 && le) && !(j > 5 && re);
                int v = pk_lds[img][rr][cc];
                a[kh][j] = (okr && okc) ? v : 0;
            }
        }
    };

    // 144 dot4 + shortcut into registers (store deferred)
    auto compute = [&](const int a[3][8], const float4 sc[4], float4 o[4]) {
#pragma unroll
        for (int c2 = 0; c2 < 4; ++c2)
#pragma unroll
            for (int p = 0; p < 4; ++p) {
                int acc = 0;
#pragma unroll
                for (int kh = 0; kh < 3; ++kh)
#pragma unroll
                    for (int kw = 0; kw < 3; ++kw)
                        acc = DOT4(a[kh][p + 2 * kw], wq[c2][kh * 3 + kw], acc);
                ((float*)&o[c2])[p] = __fadd_rn((float)acc, ((const float*)&sc[c2])[p]);
            }
    };

    int aA[3][8];
    gather(0, aA);
    float4 oA[4];
    compute(aA, scA, oA);

    pack_to_lds(xvB, 1);   // plane B (disjoint from plane A reads)
    __syncthreads();       // bar2: plane B visible (loads long since landed)

    // store A now — overlaps B's gather/compute; bar2 never waited on stores
#pragma unroll
    for (int c2 = 0; c2 < 4; ++c2)
        *(float4*)(onA + (c2 * 64 + g) * NPIX + pix0) = oA[c2];

    int aB[3][8];
    gather(1, aB);
    float4 oB[4];
    compute(aB, scB, oB);
#pragma unroll
    for (int c2 = 0; c2 < 4; ++c2)
        *(float4*)(onB + (c2 * 64 + g) * NPIX + pix0) = oB[c2];
}

extern "C" void kernel_launch(void* const* d_in, const int* in_sizes, int n_in,
                              void* d_out, int out_size, void* d_ws, size_t ws_size,
                              hipStream_t stream) {
    const float* x     = (const float*)d_in[0];
    const float* wgt   = (const float*)d_in[1];
    const float* gamma = (const float*)d_in[2];
    const float* beta  = (const float*)d_in[3];
    const float* rmean = (const float*)d_in[4];
    const float* rvar  = (const float*)d_in[5];
    float* out = (float*)d_out;

    const int N = in_sizes[0] / (CH * NPIX);  // 64
    bconv<<<(N / 2) * 64, 256, 0, stream>>>(x, wgt, gamma, beta, rmean, rvar, out);
}